// Round 23
// baseline (137.431 us; speedup 1.0000x reference)
//
#include <hip/hip_runtime.h>

// VQ-VAE vector quantizer, MI355X (gfx950).
// z: [B=32, C=256, H=32, W=32] fp32; emb: [K=1024, C=256] fp32.
// Outputs (flat f32): z_q [B,C,H,W] (8388608) | loss (1) | idx-as-float (32768).
//
// score = ||e||^2 - 2 z.e via ONE bf16 MFMA. R23 argmin: 512-thread /
// 128-pixel blocks (grid 256): per-CU B-DMA bytes HALVE vs R20's two
// 64-px blocks (one 512KB stream per CU feeds 128 px), each 32KB chunk
// feeds 2x the MFMAs per drain. 16 barriers; LDS 64KB = z tile (staged
// once, XOR-swizzled, A->registers static-index) reused as 2x32KB B dbuf.
// No min-occupancy launch bound (R21 lesson: forced cap -> silent spill).
// Top-2 as packed u64 keys; shuffle merge network gives top-3.
//   gap3 < THR -> list3: WAVE-PARALLEL full np rescan (atomicMin u64)
//   gap2 < THR -> list2: np-exact {i1,i2} compare, one wave per entry
// np-winner is within 7e-5 of the exact min; bf16 noise sigma ~2.6e-5;
// THR=2.5e-4 margins proven R3-R22.

#define BB     32
#define CDIM   256
#define HW     1024
#define KK     1024
#define NPIX   (BB * HW)

#define THR     2.5e-4f
#define LISTCAP 16384

typedef __attribute__((ext_vector_type(8))) short bf16x8;
typedef __attribute__((ext_vector_type(4))) float f32x4;
typedef unsigned long long u64;
typedef unsigned int u32;

__device__ __forceinline__ unsigned short bf16_rn(float f) {
    unsigned int u = __float_as_uint(f);
    unsigned int r = u + 0x7fffu + ((u >> 16) & 1u);   // RNE
    return (unsigned short)(r >> 16);
}
__device__ __forceinline__ f32x4 mfma16(bf16x8 a, bf16x8 b, f32x4 c) {
    return __builtin_amdgcn_mfma_f32_16x16x32_bf16(a, b, c, 0, 0, 0);
}
__device__ __forceinline__ u32 ordf(float v) {
    const u32 b = __float_as_uint(v);
    return b ^ ((u32)((int)b >> 31) | 0x80000000u);
}
__device__ __forceinline__ float unordf(u32 u) {
    const u32 b = (u & 0x80000000u) ? (u ^ 0x80000000u) : ~u;
    return __uint_as_float(b);
}
__device__ __forceinline__ u64 min64(u64 a, u64 b) { return a < b ? a : b; }
__device__ __forceinline__ u64 max64(u64 a, u64 b) { return a > b ? a : b; }

// ---------------- prep: cnt reset + bf16 swizzled emb + np-exact e-norms
// ehi 32KB-chunk layout: chunk = kt*4 + (c>>6); within chunk:
// inner = ((((c>>5)&1)*16 + k16) << 9) + (lk*16+li)*8 + cj
__global__ __launch_bounds__(256)
void prep_kernel(const float* __restrict__ emb,
                 unsigned short* __restrict__ ehi,
                 float* __restrict__ enorm, int* __restrict__ cnt) {
    const int t   = threadIdx.x;
    const int gid = blockIdx.x * 256 + t;
    if (gid == 0) { cnt[0] = 0; cnt[1] = 0; }
#pragma unroll
    for (int q = 0; q < 4; ++q) {
        const int i = gid * 4 + q;              // float4 index, 65536 total
        const int k = i >> 6;
        const int c = (i & 63) * 4;
        const float4 v = ((const float4*)emb)[i];
        ushort4 hv;
        hv.x = bf16_rn(v.x); hv.y = bf16_rn(v.y);
        hv.z = bf16_rn(v.z); hv.w = bf16_rn(v.w);
        const int kt = k >> 8, k16 = (k >> 4) & 15, li = k & 15;
        const int chunk = kt * 4 + (c >> 6);
        const int c32 = (c >> 5) & 1, lk = (c >> 3) & 3, cj = c & 7;
        const int off = chunk * 16384 + (((c32 * 16 + k16) << 9)
                      + (lk * 16 + li) * 8 + cj);
        *(ushort4*)(ehi + off) = hv;
    }
    // enorm: wave wv handles rows (blockIdx*4+wv)*4 .. +3, 16 lanes per row
    const int wv = t >> 6, lane = t & 63;
    const int row   = (blockIdx.x * 4 + wv) * 4 + (lane >> 4);
    const int chain = lane & 15;
    const int half = chain >> 3, jj = chain & 7;
    float acc = 0.f;
    {
#pragma clang fp contract(off)
        const float* er = emb + (size_t)row * CDIM + half * 128 + jj;
#pragma unroll
        for (int m = 0; m < 16; ++m) {
            const float a = er[8 * m];
            const float p = a * a;
            acc = acc + p;
        }
    }
    const int gb = lane & ~15;
    const float c0 = __shfl(acc, gb + 0, 64), c1 = __shfl(acc, gb + 1, 64);
    const float c2 = __shfl(acc, gb + 2, 64), c3 = __shfl(acc, gb + 3, 64);
    const float c4 = __shfl(acc, gb + 4, 64), c5 = __shfl(acc, gb + 5, 64);
    const float c6 = __shfl(acc, gb + 6, 64), c7 = __shfl(acc, gb + 7, 64);
    const float d0 = __shfl(acc, gb + 8, 64), d1 = __shfl(acc, gb + 9, 64);
    const float d2 = __shfl(acc, gb + 10, 64), d3 = __shfl(acc, gb + 11, 64);
    const float d4 = __shfl(acc, gb + 12, 64), d5 = __shfl(acc, gb + 13, 64);
    const float d6 = __shfl(acc, gb + 14, 64), d7 = __shfl(acc, gb + 15, 64);
    if (chain == 0) {
#pragma clang fp contract(off)
        const float L = ((c0 + c1) + (c2 + c3)) + ((c4 + c5) + (c6 + c7));
        const float R = ((d0 + d1) + (d2 + d3)) + ((d4 + d5) + (d6 + d7));
        enorm[row] = L + R;
    }
}

// ---------------------------------------------------------- MFMA argmin
// 128 px x 1024 codes; 8 waves pixel-split (16 px each); 16 chunks of
// 32KB, 2x dbuf in the SAME 64KB that held the z tile (A in registers).
__global__ __launch_bounds__(512)
void argmin_mfma_kernel(const float* __restrict__ z,
                        const unsigned short* __restrict__ ehi,
                        const float* __restrict__ enorm,
                        int* __restrict__ idx_i, float* __restrict__ idx_f,
                        int* __restrict__ cnt, int* __restrict__ list2,
                        int* __restrict__ list3, u64* __restrict__ minslot) {
    __shared__ __align__(16) unsigned short blds[2][16384];   // 64 KB

    const int t    = threadIdx.x;
    const int px0  = blockIdx.x * 128;
    const int b    = px0 >> 10;
    const int hw0  = px0 & 1023;
    const int wn   = t >> 6;            // 0..7
    const int lane = t & 63;
    const int li   = lane & 15;
    const int lk   = lane >> 4;

    unsigned short* flat = &blds[0][0];      // 32768 shorts = 128px x 256c

    // ---- stage z [px][c] XOR-swizzled (128 px)
#pragma unroll
    for (int it = 0; it < 16; ++it) {
        const int c     = it * 16 + (t >> 5);
        const int chunk = t & 31;            // 32 float4s cover 128 px
        const f32x4 v = __builtin_nontemporal_load(
            (const f32x4*)(z + ((size_t)(b * 256 + c)) * 1024 + hw0 + chunk * 4));
#pragma unroll
        for (int i = 0; i < 4; ++i) {
            const int ie = (i + chunk) & 3;
            const int px = chunk * 4 + ie;
            flat[px * 256 + (c ^ ((px & 7) << 3))] = bf16_rn(-2.0f * v[ie]);
        }
    }
    __syncthreads();

    // ---- A fragments -> registers (compile-time indexing)
    bf16x8 Ar[8];
    {
        const int row = wn * 16 + li;        // rows 0..127
#pragma unroll
        for (int ks = 0; ks < 8; ++ks) {
            const int c0 = (lk * 8 + ks * 32) ^ ((li & 7) << 3);
            Ar[ks] = *(const bf16x8*)&flat[row * 256 + c0];
        }
    }
    __syncthreads();          // all A reads done before B overwrites

    // stage 32KB chunk cc into blds[buf]: 32 parts of 1KB, 4 per wave
    auto stage = [&](int cc, int buf) {
#pragma unroll
        for (int p = 0; p < 4; ++p) {
            const int part = wn * 4 + p;
            const unsigned short* gsl = ehi + (size_t)cc * 16384
                                      + part * 512 + lane * 8;
            unsigned short* ldst = &blds[buf][part * 512];
            __builtin_amdgcn_global_load_lds(
                (const __attribute__((address_space(1))) unsigned int*)(const void*)gsl,
                (__attribute__((address_space(3))) unsigned int*)(void*)ldst,
                16, 0, 0);
        }
    };

    stage(0, 0);
    __syncthreads();          // chunk 0 landed

    u64 K1[4], K2[4];
#pragma unroll
    for (int r = 0; r < 4; ++r) { K1[r] = ~0ull; K2[r] = ~0ull; }

    f32x4 acc[16];

#pragma unroll
    for (int cc = 0; cc < 16; ++cc) {        // chunk = kt*4 + c64 (unrolled)
        const int kt  = cc >> 2;
        const int c64 = cc & 3;
        const int buf = cc & 1;

        if (c64 == 0) {
#pragma unroll
            for (int ni = 0; ni < 16; ++ni) {
                const float en = enorm[kt * 256 + ni * 16 + li];
                acc[ni][0] = en; acc[ni][1] = en; acc[ni][2] = en; acc[ni][3] = en;
            }
        }

        if (cc < 15) stage(cc + 1, buf ^ 1);

#pragma unroll
        for (int ks2 = 0; ks2 < 2; ++ks2) {
            const bf16x8 A = Ar[c64 * 2 + ks2];          // static index
#pragma unroll
            for (int ni = 0; ni < 16; ++ni) {
                const bf16x8 Bf = *(const bf16x8*)
                    &blds[buf][(ks2 * 16 + ni) * 512 + lane * 8];
                acc[ni] = mfma16(A, Bf, acc[ni]);
            }
        }

        if (c64 == 3) {
#pragma unroll
            for (int ni = 0; ni < 16; ++ni) {
                const u32 k = (u32)(kt * 256 + ni * 16 + li);
#pragma unroll
                for (int r = 0; r < 4; ++r) {
                    const u64 key = ((u64)ordf(acc[ni][r]) << 32) | k;
                    const u64 mx  = max64(K1[r], key);
                    K1[r] = min64(K1[r], key);
                    K2[r] = min64(K2[r], mx);
                }
            }
        }
        __syncthreads();
    }

    // cross-lane merge over the 16 li lanes: 3-list merge network
    u64 K3[4];
#pragma unroll
    for (int r = 0; r < 4; ++r) K3[r] = ~0ull;
#pragma unroll
    for (int m = 1; m < 16; m <<= 1) {
#pragma unroll
        for (int r = 0; r < 4; ++r) {
            const u64 b1 = __shfl_xor(K1[r], m, 64);
            const u64 b2 = __shfl_xor(K2[r], m, 64);
            const u64 b3 = __shfl_xor(K3[r], m, 64);
            const u64 m1 = min64(K1[r], b1), M1 = max64(K1[r], b1);
            const u64 m2 = min64(K2[r], b2), M2 = max64(K2[r], b2);
            K1[r] = m1;
            K2[r] = min64(M1, m2);
            K3[r] = min64(max64(M1, m2), min64(M2, min64(K3[r], b3)));
        }
    }
    if (li == 0) {
#pragma unroll
        for (int r = 0; r < 4; ++r) {
            const int n  = px0 + wn * 16 + lk * 4 + r;
            const int i1 = (int)(K1[r] & 0xffffffffu);
            const int i2 = (int)(K2[r] & 0xffffffffu);
            const float v1 = unordf((u32)(K1[r] >> 32));
            const float v2 = unordf((u32)(K2[r] >> 32));
            const float v3 = unordf((u32)(K3[r] >> 32));
            idx_i[n] = i1;
            idx_f[n] = (float)i1;
            if (v3 - v1 < THR) {                  // 3+ candidates: full rescan
                const int slot = atomicAdd(&cnt[1], 1);
                if (slot < LISTCAP) { list3[slot] = n; minslot[slot] = ~0ull; }
            } else if (v2 - v1 < THR) {           // exactly 2 candidates
                const int slot = atomicAdd(&cnt[0], 1);
                if (slot < LISTCAP) list2[slot] = n | (i2 << 17);
            }
        }
    }
}

// ------------- npfix23: role-split merged fixup (one launch)
//  blocks [0,512):   list2 — one wave per entry, np-exact {i1,i2} compare
//  blocks [512,768): list3 — wave-parallel full np rescan via atomicMin
__global__ __launch_bounds__(256)
void npfix23_kernel(const float* __restrict__ z, const float* __restrict__ emb,
                    const float* __restrict__ enorm_np,
                    const int* __restrict__ cnt, const int* __restrict__ list2,
                    const int* __restrict__ list3,
                    int* __restrict__ idx_i, float* __restrict__ idx_f,
                    u64* __restrict__ minslot) {
    const int t = threadIdx.x, wv = t >> 6, lane = t & 63;

    if (blockIdx.x < 512) {
        const int nflag = min(cnt[0], LISTCAP);
        for (int idx = blockIdx.x * 4 + wv; idx < nflag; idx += 512 * 4) {
            const int e  = list2[idx];
            const int n  = e & 0x1FFFF;
            const int k2 = e >> 17;
            const int k1 = idx_i[n];
            const float* zb = z + (size_t)(n >> 10) * (CDIM * HW) + (n & 1023);

            float acc = 0.f;
            if (lane < 8) {
                const int cand = lane >> 2, j = lane & 3;
                const int k = cand ? k2 : k1;
                const float* er = emb + (size_t)k * CDIM + j;
                {
#pragma clang fp contract(off)
#pragma unroll
                    for (int m = 0; m < 64; ++m) {
                        const float ev = er[4 * m];
                        const float zv = zb[(size_t)(4 * m + j) * HW];
                        const float p  = ev * zv;
                        acc = acc + p;
                    }
                }
            } else if (lane < 24) {
                const int j = lane - 8;
                const int half = j >> 3, jj = j & 7;
                {
#pragma clang fp contract(off)
#pragma unroll
                    for (int m = 0; m < 16; ++m) {
                        const int c = half * 128 + 8 * m + jj;
                        const float a = zb[(size_t)c * HW];
                        const float p = a * a;
                        acc = acc + p;
                    }
                }
            }

            const float d10 = __shfl(acc, 0, 64), d11 = __shfl(acc, 1, 64);
            const float d12 = __shfl(acc, 2, 64), d13 = __shfl(acc, 3, 64);
            const float d20 = __shfl(acc, 4, 64), d21 = __shfl(acc, 5, 64);
            const float d22 = __shfl(acc, 6, 64), d23 = __shfl(acc, 7, 64);
            const float r0 = __shfl(acc,  8, 64), r1 = __shfl(acc,  9, 64);
            const float r2 = __shfl(acc, 10, 64), r3 = __shfl(acc, 11, 64);
            const float r4 = __shfl(acc, 12, 64), r5 = __shfl(acc, 13, 64);
            const float r6 = __shfl(acc, 14, 64), r7 = __shfl(acc, 15, 64);
            const float s0 = __shfl(acc, 16, 64), s1 = __shfl(acc, 17, 64);
            const float s2 = __shfl(acc, 18, 64), s3 = __shfl(acc, 19, 64);
            const float s4 = __shfl(acc, 20, 64), s5 = __shfl(acc, 21, 64);
            const float s6 = __shfl(acc, 22, 64), s7 = __shfl(acc, 23, 64);
            if (lane == 0) {
#pragma clang fp contract(off)
                const float L   = ((r0 + r1) + (r2 + r3)) + ((r4 + r5) + (r6 + r7));
                const float R   = ((s0 + s1) + (s2 + s3)) + ((s4 + s5) + (s6 + s7));
                const float znp = L + R;
                const float dot1 = (d10 + d11) + (d12 + d13);
                const float dot2 = (d20 + d21) + (d22 + d23);
                const float S1 = znp + enorm_np[k1];
                const float S2 = znp + enorm_np[k2];
                const float tw1 = 2.0f * dot1;
                const float tw2 = 2.0f * dot2;
                const float dd1 = S1 - tw1;
                const float dd2 = S2 - tw2;
                const bool take2 = (dd2 < dd1) || (dd2 == dd1 && k2 < k1);
                const int bk = take2 ? k2 : k1;
                idx_i[n] = bk;
                idx_f[n] = (float)bk;
            }
        }
    } else {
        const int bid = blockIdx.x - 512;          // 256 blocks
        const int nflag = min(cnt[1], LISTCAP);
        const int ntask = nflag * 64;
        for (int task = bid * 4 + wv; task < ntask; task += 256 * 4) {
            const int ei  = task >> 6;
            const int grp = task & 63;
            const int n   = list3[ei];
            const float* zb = z + (size_t)(n >> 10) * (CDIM * HW) + (n & 1023);
            const int k = grp * 16 + (lane >> 2);
            const int j = lane & 3;

            float acc = 0.f;
            {
#pragma clang fp contract(off)
                const float* er = emb + (size_t)k * CDIM + j;
#pragma unroll
                for (int m = 0; m < 64; ++m) {
                    const float ev = er[4 * m];
                    const float zv = zb[(size_t)(4 * m + j) * HW];
                    const float p  = ev * zv;
                    acc = acc + p;
                }
            }
            float acc2 = 0.f;
            if (lane < 16) {
                const int half = lane >> 3, jj = lane & 7;
                {
#pragma clang fp contract(off)
#pragma unroll
                    for (int m = 0; m < 16; ++m) {
                        const int c = half * 128 + 8 * m + jj;
                        const float a = zb[(size_t)c * HW];
                        const float p = a * a;
                        acc2 = acc2 + p;
                    }
                }
            }
            const float r0 = __shfl(acc2, 0, 64), r1 = __shfl(acc2, 1, 64);
            const float r2 = __shfl(acc2, 2, 64), r3 = __shfl(acc2, 3, 64);
            const float r4 = __shfl(acc2, 4, 64), r5 = __shfl(acc2, 5, 64);
            const float r6 = __shfl(acc2, 6, 64), r7 = __shfl(acc2, 7, 64);
            const float s0 = __shfl(acc2,  8, 64), s1 = __shfl(acc2,  9, 64);
            const float s2 = __shfl(acc2, 10, 64), s3 = __shfl(acc2, 11, 64);
            const float s4 = __shfl(acc2, 12, 64), s5 = __shfl(acc2, 13, 64);
            const float s6 = __shfl(acc2, 14, 64), s7 = __shfl(acc2, 15, 64);
            float znp;
            {
#pragma clang fp contract(off)
                const float L = ((r0 + r1) + (r2 + r3)) + ((r4 + r5) + (r6 + r7));
                const float R = ((s0 + s1) + (s2 + s3)) + ((s4 + s5) + (s6 + s7));
                znp = L + R;
            }
            const int lb = lane & ~3;
            const float l0 = __shfl(acc, lb + 0, 64), l1 = __shfl(acc, lb + 1, 64);
            const float l2 = __shfl(acc, lb + 2, 64), l3 = __shfl(acc, lb + 3, 64);
            u64 key = ~0ull;
            {
#pragma clang fp contract(off)
                const float dot = (l0 + l1) + (l2 + l3);
                const float S   = znp + enorm_np[k];
                const float tw  = 2.0f * dot;
                const float d   = S - tw;
                if ((lane & 3) == 0) key = ((u64)ordf(d) << 32) | (u32)k;
            }
#pragma unroll
            for (int m = 1; m < 64; m <<= 1) key = min64(key, __shfl_xor(key, m, 64));
            if (lane == 0) atomicMin(&minslot[ei], key);
        }
    }
}

// ------------- fin3: write idx for list3 entries from minslot
__global__ void fin3_kernel(const int* __restrict__ cnt,
                            const int* __restrict__ list3,
                            const u64* __restrict__ minslot,
                            int* __restrict__ idx_i, float* __restrict__ idx_f) {
    const int nflag = min(cnt[1], LISTCAP);
    for (int i = threadIdx.x; i < nflag; i += 256) {
        const u64 key = minslot[i];
        const int k = (int)(key & 0xffffffffu);
        const int n = list3[i];
        idx_i[n] = k;
        idx_f[n] = (float)k;
    }
}

// ---------------------------------------------------------------- z_q + loss
// 512 blocks: blk = b*16 + cg (16-channel group).
__global__ __launch_bounds__(256)
void zq_loss_kernel(const float* __restrict__ z, const float* __restrict__ emb,
                    const int* __restrict__ idx_i, float* __restrict__ zq,
                    double* __restrict__ lpart) {
    const int blk = blockIdx.x;
    const int b   = blk >> 4;
    const int cg  = blk & 15;
    const int t   = threadIdx.x;
    const int hw  = t * 4;
    const int n0  = b * HW + hw;

    const float* e0 = emb + (size_t)idx_i[n0 + 0] * CDIM + cg * 16;
    const float* e1 = emb + (size_t)idx_i[n0 + 1] * CDIM + cg * 16;
    const float* e2 = emb + (size_t)idx_i[n0 + 2] * CDIM + cg * 16;
    const float* e3 = emb + (size_t)idx_i[n0 + 3] * CDIM + cg * 16;

    const size_t base = ((size_t)b * CDIM + cg * 16) * HW + hw;
    const float* zb = z + base;
    float*       ob = zq + base;

    float ls = 0.f;
#pragma unroll
    for (int c4 = 0; c4 < 4; ++c4) {
        const float4 a0 = *(const float4*)(e0 + 4 * c4);
        const float4 a1 = *(const float4*)(e1 + 4 * c4);
        const float4 a2 = *(const float4*)(e2 + 4 * c4);
        const float4 a3 = *(const float4*)(e3 + 4 * c4);
        const float av0[4] = {a0.x, a0.y, a0.z, a0.w};
        const float av1[4] = {a1.x, a1.y, a1.z, a1.w};
        const float av2[4] = {a2.x, a2.y, a2.z, a2.w};
        const float av3[4] = {a3.x, a3.y, a3.z, a3.w};
#pragma unroll
        for (int cj = 0; cj < 4; ++cj) {
            const size_t off = (size_t)(c4 * 4 + cj) * HW;
            const f32x4 zv = __builtin_nontemporal_load((const f32x4*)(zb + off));
            f32x4 o;
            o[0] = av0[cj]; o[1] = av1[cj]; o[2] = av2[cj]; o[3] = av3[cj];
            __builtin_nontemporal_store(o, (f32x4*)(ob + off));
            const float d0 = o[0] - zv[0], d1 = o[1] - zv[1];
            const float d2 = o[2] - zv[2], d3 = o[3] - zv[3];
            ls += d0 * d0 + d1 * d1 + d2 * d2 + d3 * d3;
        }
    }

    __shared__ float red[256];
    red[t] = ls;
    __syncthreads();
    if (t < 128) red[t] += red[t + 128];
    __syncthreads();
    if (t < 64) {
        float s = red[t] + red[t + 64];
#pragma unroll
        for (int off = 32; off > 0; off >>= 1) s += __shfl_down(s, off, 64);
        if (t == 0) lpart[blk] = (double)s;
    }
}

__global__ void loss_fin_kernel(const double* __restrict__ lpart,
                                float* __restrict__ loss_out) {
    const int t = threadIdx.x;   // 64 threads; 512 partials
    double s = 0.0;
#pragma unroll
    for (int i = 0; i < 8; ++i) s += lpart[t * 8 + i];
#pragma unroll
    for (int off = 32; off > 0; off >>= 1) s += __shfl_down(s, off, 64);
    if (t == 0)
        loss_out[0] = (float)(0.25 * s / (double)((size_t)BB * CDIM * HW));
}

// ---------------------------------------------------------------- launch
extern "C" void kernel_launch(void* const* d_in, const int* in_sizes, int n_in,
                              void* d_out, int out_size, void* d_ws, size_t ws_size,
                              hipStream_t stream) {
    const float* z   = (const float*)d_in[0];
    const float* emb = (const float*)d_in[1];

    float* out  = (float*)d_out;
    float* zq   = out;
    float* loss = out + (size_t)BB * CDIM * HW;
    float* idxf = loss + 1;

    char* ws = (char*)d_ws;
    int*            idx_i   = (int*)(ws);                      // 131072 B
    float*          enorm   = (float*)(ws + 131072);           // 4096 B
    double*         lpart   = (double*)(ws + 135168);          // 4096 B
    int*            cnt     = (int*)(ws + 139264);             // 256 B
    int*            list2   = (int*)(ws + 139520);             // 65536 B
    int*            list3   = (int*)(ws + 205056);             // 65536 B
    unsigned short* ehi     = (unsigned short*)(ws + 270592);  // 524288 B
    u64*            minslot = (u64*)(ws + 794880);             // 131072 B

    prep_kernel<<<64, 256, 0, stream>>>(emb, ehi, enorm, cnt);

    argmin_mfma_kernel<<<NPIX / 128, 512, 0, stream>>>(z, ehi, enorm,
                                                       idx_i, idxf, cnt,
                                                       list2, list3, minslot);
    npfix23_kernel<<<768, 256, 0, stream>>>(z, emb, enorm, cnt, list2, list3,
                                            idx_i, idxf, minslot);
    fin3_kernel<<<1, 256, 0, stream>>>(cnt, list3, minslot, idx_i, idxf);

    zq_loss_kernel<<<BB * 16, 256, 0, stream>>>(z, emb, idx_i, zq, lpart);
    loss_fin_kernel<<<1, 64, 0, stream>>>(lpart, loss);
}

// Round 24
// 134.158 us; speedup vs baseline: 1.0244x; 1.0244x over previous
//
#include <hip/hip_runtime.h>

// VQ-VAE vector quantizer, MI355X (gfx950).  FINAL = R20/R22 configuration
// (reproduced twice: 134.3 / 134.5 us, absmax 3.8e-6).
// z: [B=32, C=256, H=32, W=32] fp32; emb: [K=1024, C=256] fp32.
// Outputs (flat f32): z_q [B,C,H,W] (8388608) | loss (1) | idx-as-float (32768).
//
// score = ||e||^2 - 2 z.e via ONE bf16 MFMA. argmin: 32KB chunks
// (64 c x 256 codes) -> 16 barriers; LDS 64KB = 2x32KB dbuf; z staged
// XOR-swizzled into the B region ONCE, A-fragments -> registers with
// compile-time indexing, region reused. 2 blocks/CU, VGPR 92, no spill.
// Geometry matrix fully probed: K-split (R18: dup z staging), 4-blk
// occupancy bound (R21: silent spill), counted-vmcnt (R13: neutral),
// 512-thread/128px (R23: bank conflicts + barrier coupling). This is the
// empirical optimum of the structure.
// Top-2 as packed u64 keys; shuffle merge network gives top-3.
//   gap3 < THR -> list3: WAVE-PARALLEL full np rescan (atomicMin u64)
//   gap2 < THR -> list2: np-exact {i1,i2} compare, one wave per entry
// np-winner is within 7e-5 of the exact min; bf16 noise sigma ~2.6e-5;
// THR=2.5e-4 margins proven R3-R23.

#define BB     32
#define CDIM   256
#define HW     1024
#define KK     1024
#define NPIX   (BB * HW)

#define THR     2.5e-4f
#define LISTCAP 16384

typedef __attribute__((ext_vector_type(8))) short bf16x8;
typedef __attribute__((ext_vector_type(4))) float f32x4;
typedef unsigned long long u64;
typedef unsigned int u32;

__device__ __forceinline__ unsigned short bf16_rn(float f) {
    unsigned int u = __float_as_uint(f);
    unsigned int r = u + 0x7fffu + ((u >> 16) & 1u);   // RNE
    return (unsigned short)(r >> 16);
}
__device__ __forceinline__ f32x4 mfma16(bf16x8 a, bf16x8 b, f32x4 c) {
    return __builtin_amdgcn_mfma_f32_16x16x32_bf16(a, b, c, 0, 0, 0);
}
__device__ __forceinline__ u32 ordf(float v) {
    const u32 b = __float_as_uint(v);
    return b ^ ((u32)((int)b >> 31) | 0x80000000u);
}
__device__ __forceinline__ float unordf(u32 u) {
    const u32 b = (u & 0x80000000u) ? (u ^ 0x80000000u) : ~u;
    return __uint_as_float(b);
}
__device__ __forceinline__ u64 min64(u64 a, u64 b) { return a < b ? a : b; }
__device__ __forceinline__ u64 max64(u64 a, u64 b) { return a > b ? a : b; }

// ---------------- prep: cnt reset + bf16 swizzled emb + np-exact e-norms
// ehi 32KB-chunk layout: chunk = kt*4 + (c>>6); within chunk:
// inner = ((((c>>5)&1)*16 + k16) << 9) + (lk*16+li)*8 + cj
__global__ __launch_bounds__(256)
void prep_kernel(const float* __restrict__ emb,
                 unsigned short* __restrict__ ehi,
                 float* __restrict__ enorm, int* __restrict__ cnt) {
    const int t   = threadIdx.x;
    const int gid = blockIdx.x * 256 + t;
    if (gid == 0) { cnt[0] = 0; cnt[1] = 0; }
#pragma unroll
    for (int q = 0; q < 4; ++q) {
        const int i = gid * 4 + q;              // float4 index, 65536 total
        const int k = i >> 6;
        const int c = (i & 63) * 4;
        const float4 v = ((const float4*)emb)[i];
        ushort4 hv;
        hv.x = bf16_rn(v.x); hv.y = bf16_rn(v.y);
        hv.z = bf16_rn(v.z); hv.w = bf16_rn(v.w);
        const int kt = k >> 8, k16 = (k >> 4) & 15, li = k & 15;
        const int chunk = kt * 4 + (c >> 6);
        const int c32 = (c >> 5) & 1, lk = (c >> 3) & 3, cj = c & 7;
        const int off = chunk * 16384 + (((c32 * 16 + k16) << 9)
                      + (lk * 16 + li) * 8 + cj);
        *(ushort4*)(ehi + off) = hv;
    }
    // enorm: wave wv handles rows (blockIdx*4+wv)*4 .. +3, 16 lanes per row
    const int wv = t >> 6, lane = t & 63;
    const int row   = (blockIdx.x * 4 + wv) * 4 + (lane >> 4);
    const int chain = lane & 15;
    const int half = chain >> 3, jj = chain & 7;
    float acc = 0.f;
    {
#pragma clang fp contract(off)
        const float* er = emb + (size_t)row * CDIM + half * 128 + jj;
#pragma unroll
        for (int m = 0; m < 16; ++m) {
            const float a = er[8 * m];
            const float p = a * a;
            acc = acc + p;
        }
    }
    const int gb = lane & ~15;
    const float c0 = __shfl(acc, gb + 0, 64), c1 = __shfl(acc, gb + 1, 64);
    const float c2 = __shfl(acc, gb + 2, 64), c3 = __shfl(acc, gb + 3, 64);
    const float c4 = __shfl(acc, gb + 4, 64), c5 = __shfl(acc, gb + 5, 64);
    const float c6 = __shfl(acc, gb + 6, 64), c7 = __shfl(acc, gb + 7, 64);
    const float d0 = __shfl(acc, gb + 8, 64), d1 = __shfl(acc, gb + 9, 64);
    const float d2 = __shfl(acc, gb + 10, 64), d3 = __shfl(acc, gb + 11, 64);
    const float d4 = __shfl(acc, gb + 12, 64), d5 = __shfl(acc, gb + 13, 64);
    const float d6 = __shfl(acc, gb + 14, 64), d7 = __shfl(acc, gb + 15, 64);
    if (chain == 0) {
#pragma clang fp contract(off)
        const float L = ((c0 + c1) + (c2 + c3)) + ((c4 + c5) + (c6 + c7));
        const float R = ((d0 + d1) + (d2 + d3)) + ((d4 + d5) + (d6 + d7));
        enorm[row] = L + R;
    }
}

// ---------------------------------------------------------- MFMA argmin
// 64 px x 1024 codes; 4 waves pixel-split; 16 chunks of 32KB, 2x dbuf.
// z staged once into blds[0] region, A -> registers (static idx), reuse.
__global__ __launch_bounds__(256, 2)
void argmin_mfma_kernel(const float* __restrict__ z,
                        const unsigned short* __restrict__ ehi,
                        const float* __restrict__ enorm,
                        int* __restrict__ idx_i, float* __restrict__ idx_f,
                        int* __restrict__ cnt, int* __restrict__ list2,
                        int* __restrict__ list3, u64* __restrict__ minslot) {
    __shared__ __align__(16) unsigned short blds[2][16384];   // 64 KB

    const int t    = threadIdx.x;
    const int px0  = blockIdx.x * 64;
    const int b    = px0 >> 10;
    const int hw0  = px0 & 1023;
    const int wn   = t >> 6;
    const int lane = t & 63;
    const int li   = lane & 15;
    const int lk   = lane >> 4;

    unsigned short* flat = &blds[0][0];      // 16384 shorts = 64px x 256c

    // ---- stage z [px][c] XOR-swizzled
#pragma unroll
    for (int it = 0; it < 16; ++it) {
        const int c     = it * 16 + (t >> 4);
        const int chunk = t & 15;
        const f32x4 v = __builtin_nontemporal_load(
            (const f32x4*)(z + ((size_t)(b * 256 + c)) * 1024 + hw0 + chunk * 4));
#pragma unroll
        for (int i = 0; i < 4; ++i) {
            const int ie = (i + chunk) & 3;
            const int px = chunk * 4 + ie;
            flat[px * 256 + (c ^ ((px & 7) << 3))] = bf16_rn(-2.0f * v[ie]);
        }
    }
    __syncthreads();

    // ---- A fragments -> registers (compile-time indexing)
    bf16x8 Ar[8];
    {
        const int row = wn * 16 + li;
#pragma unroll
        for (int ks = 0; ks < 8; ++ks) {
            const int c0 = (lk * 8 + ks * 32) ^ ((li & 7) << 3);
            Ar[ks] = *(const bf16x8*)&flat[row * 256 + c0];
        }
    }
    __syncthreads();          // all A reads done before B overwrites

    // stage 32KB chunk cc into blds[buf]: 32 parts of 1KB, 8 per wave
    auto stage = [&](int cc, int buf) {
#pragma unroll
        for (int p = 0; p < 8; ++p) {
            const int part = wn * 8 + p;
            const unsigned short* gsl = ehi + (size_t)cc * 16384
                                      + part * 512 + lane * 8;
            unsigned short* ldst = &blds[buf][part * 512];
            __builtin_amdgcn_global_load_lds(
                (const __attribute__((address_space(1))) unsigned int*)(const void*)gsl,
                (__attribute__((address_space(3))) unsigned int*)(void*)ldst,
                16, 0, 0);
        }
    };

    stage(0, 0);
    __syncthreads();          // chunk 0 landed

    u64 K1[4], K2[4];
#pragma unroll
    for (int r = 0; r < 4; ++r) { K1[r] = ~0ull; K2[r] = ~0ull; }

    f32x4 acc[16];

#pragma unroll
    for (int cc = 0; cc < 16; ++cc) {        // chunk = kt*4 + c64 (unrolled)
        const int kt  = cc >> 2;
        const int c64 = cc & 3;
        const int buf = cc & 1;

        if (c64 == 0) {
#pragma unroll
            for (int ni = 0; ni < 16; ++ni) {
                const float en = enorm[kt * 256 + ni * 16 + li];
                acc[ni][0] = en; acc[ni][1] = en; acc[ni][2] = en; acc[ni][3] = en;
            }
        }

        if (cc < 15) stage(cc + 1, buf ^ 1);

#pragma unroll
        for (int ks2 = 0; ks2 < 2; ++ks2) {
            const bf16x8 A = Ar[c64 * 2 + ks2];          // static index
#pragma unroll
            for (int ni = 0; ni < 16; ++ni) {
                const bf16x8 Bf = *(const bf16x8*)
                    &blds[buf][(ks2 * 16 + ni) * 512 + lane * 8];
                acc[ni] = mfma16(A, Bf, acc[ni]);
            }
        }

        if (c64 == 3) {
#pragma unroll
            for (int ni = 0; ni < 16; ++ni) {
                const u32 k = (u32)(kt * 256 + ni * 16 + li);
#pragma unroll
                for (int r = 0; r < 4; ++r) {
                    const u64 key = ((u64)ordf(acc[ni][r]) << 32) | k;
                    const u64 mx  = max64(K1[r], key);
                    K1[r] = min64(K1[r], key);
                    K2[r] = min64(K2[r], mx);
                }
            }
        }
        __syncthreads();
    }

    // cross-lane merge over the 16 li lanes: 3-list merge network
    u64 K3[4];
#pragma unroll
    for (int r = 0; r < 4; ++r) K3[r] = ~0ull;
#pragma unroll
    for (int m = 1; m < 16; m <<= 1) {
#pragma unroll
        for (int r = 0; r < 4; ++r) {
            const u64 b1 = __shfl_xor(K1[r], m, 64);
            const u64 b2 = __shfl_xor(K2[r], m, 64);
            const u64 b3 = __shfl_xor(K3[r], m, 64);
            const u64 m1 = min64(K1[r], b1), M1 = max64(K1[r], b1);
            const u64 m2 = min64(K2[r], b2), M2 = max64(K2[r], b2);
            K1[r] = m1;
            K2[r] = min64(M1, m2);
            K3[r] = min64(max64(M1, m2), min64(M2, min64(K3[r], b3)));
        }
    }
    if (li == 0) {
#pragma unroll
        for (int r = 0; r < 4; ++r) {
            const int n  = px0 + wn * 16 + lk * 4 + r;
            const int i1 = (int)(K1[r] & 0xffffffffu);
            const int i2 = (int)(K2[r] & 0xffffffffu);
            const float v1 = unordf((u32)(K1[r] >> 32));
            const float v2 = unordf((u32)(K2[r] >> 32));
            const float v3 = unordf((u32)(K3[r] >> 32));
            idx_i[n] = i1;
            idx_f[n] = (float)i1;
            if (v3 - v1 < THR) {                  // 3+ candidates: full rescan
                const int slot = atomicAdd(&cnt[1], 1);
                if (slot < LISTCAP) { list3[slot] = n; minslot[slot] = ~0ull; }
            } else if (v2 - v1 < THR) {           // exactly 2 candidates
                const int slot = atomicAdd(&cnt[0], 1);
                if (slot < LISTCAP) list2[slot] = n | (i2 << 17);
            }
        }
    }
}

// ------------- npfix23: role-split merged fixup (one launch)
//  blocks [0,512):   list2 — one wave per entry, np-exact {i1,i2} compare
//  blocks [512,768): list3 — wave-parallel full np rescan via atomicMin
__global__ __launch_bounds__(256)
void npfix23_kernel(const float* __restrict__ z, const float* __restrict__ emb,
                    const float* __restrict__ enorm_np,
                    const int* __restrict__ cnt, const int* __restrict__ list2,
                    const int* __restrict__ list3,
                    int* __restrict__ idx_i, float* __restrict__ idx_f,
                    u64* __restrict__ minslot) {
    const int t = threadIdx.x, wv = t >> 6, lane = t & 63;

    if (blockIdx.x < 512) {
        const int nflag = min(cnt[0], LISTCAP);
        for (int idx = blockIdx.x * 4 + wv; idx < nflag; idx += 512 * 4) {
            const int e  = list2[idx];
            const int n  = e & 0x1FFFF;
            const int k2 = e >> 17;
            const int k1 = idx_i[n];
            const float* zb = z + (size_t)(n >> 10) * (CDIM * HW) + (n & 1023);

            float acc = 0.f;
            if (lane < 8) {
                const int cand = lane >> 2, j = lane & 3;
                const int k = cand ? k2 : k1;
                const float* er = emb + (size_t)k * CDIM + j;
                {
#pragma clang fp contract(off)
#pragma unroll
                    for (int m = 0; m < 64; ++m) {
                        const float ev = er[4 * m];
                        const float zv = zb[(size_t)(4 * m + j) * HW];
                        const float p  = ev * zv;
                        acc = acc + p;
                    }
                }
            } else if (lane < 24) {
                const int j = lane - 8;
                const int half = j >> 3, jj = j & 7;
                {
#pragma clang fp contract(off)
#pragma unroll
                    for (int m = 0; m < 16; ++m) {
                        const int c = half * 128 + 8 * m + jj;
                        const float a = zb[(size_t)c * HW];
                        const float p = a * a;
                        acc = acc + p;
                    }
                }
            }

            const float d10 = __shfl(acc, 0, 64), d11 = __shfl(acc, 1, 64);
            const float d12 = __shfl(acc, 2, 64), d13 = __shfl(acc, 3, 64);
            const float d20 = __shfl(acc, 4, 64), d21 = __shfl(acc, 5, 64);
            const float d22 = __shfl(acc, 6, 64), d23 = __shfl(acc, 7, 64);
            const float r0 = __shfl(acc,  8, 64), r1 = __shfl(acc,  9, 64);
            const float r2 = __shfl(acc, 10, 64), r3 = __shfl(acc, 11, 64);
            const float r4 = __shfl(acc, 12, 64), r5 = __shfl(acc, 13, 64);
            const float r6 = __shfl(acc, 14, 64), r7 = __shfl(acc, 15, 64);
            const float s0 = __shfl(acc, 16, 64), s1 = __shfl(acc, 17, 64);
            const float s2 = __shfl(acc, 18, 64), s3 = __shfl(acc, 19, 64);
            const float s4 = __shfl(acc, 20, 64), s5 = __shfl(acc, 21, 64);
            const float s6 = __shfl(acc, 22, 64), s7 = __shfl(acc, 23, 64);
            if (lane == 0) {
#pragma clang fp contract(off)
                const float L   = ((r0 + r1) + (r2 + r3)) + ((r4 + r5) + (r6 + r7));
                const float R   = ((s0 + s1) + (s2 + s3)) + ((s4 + s5) + (s6 + s7));
                const float znp = L + R;
                const float dot1 = (d10 + d11) + (d12 + d13);
                const float dot2 = (d20 + d21) + (d22 + d23);
                const float S1 = znp + enorm_np[k1];
                const float S2 = znp + enorm_np[k2];
                const float tw1 = 2.0f * dot1;
                const float tw2 = 2.0f * dot2;
                const float dd1 = S1 - tw1;
                const float dd2 = S2 - tw2;
                const bool take2 = (dd2 < dd1) || (dd2 == dd1 && k2 < k1);
                const int bk = take2 ? k2 : k1;
                idx_i[n] = bk;
                idx_f[n] = (float)bk;
            }
        }
    } else {
        const int bid = blockIdx.x - 512;          // 256 blocks
        const int nflag = min(cnt[1], LISTCAP);
        const int ntask = nflag * 64;
        for (int task = bid * 4 + wv; task < ntask; task += 256 * 4) {
            const int ei  = task >> 6;
            const int grp = task & 63;
            const int n   = list3[ei];
            const float* zb = z + (size_t)(n >> 10) * (CDIM * HW) + (n & 1023);
            const int k = grp * 16 + (lane >> 2);
            const int j = lane & 3;

            float acc = 0.f;
            {
#pragma clang fp contract(off)
                const float* er = emb + (size_t)k * CDIM + j;
#pragma unroll
                for (int m = 0; m < 64; ++m) {
                    const float ev = er[4 * m];
                    const float zv = zb[(size_t)(4 * m + j) * HW];
                    const float p  = ev * zv;
                    acc = acc + p;
                }
            }
            float acc2 = 0.f;
            if (lane < 16) {
                const int half = lane >> 3, jj = lane & 7;
                {
#pragma clang fp contract(off)
#pragma unroll
                    for (int m = 0; m < 16; ++m) {
                        const int c = half * 128 + 8 * m + jj;
                        const float a = zb[(size_t)c * HW];
                        const float p = a * a;
                        acc2 = acc2 + p;
                    }
                }
            }
            const float r0 = __shfl(acc2, 0, 64), r1 = __shfl(acc2, 1, 64);
            const float r2 = __shfl(acc2, 2, 64), r3 = __shfl(acc2, 3, 64);
            const float r4 = __shfl(acc2, 4, 64), r5 = __shfl(acc2, 5, 64);
            const float r6 = __shfl(acc2, 6, 64), r7 = __shfl(acc2, 7, 64);
            const float s0 = __shfl(acc2,  8, 64), s1 = __shfl(acc2,  9, 64);
            const float s2 = __shfl(acc2, 10, 64), s3 = __shfl(acc2, 11, 64);
            const float s4 = __shfl(acc2, 12, 64), s5 = __shfl(acc2, 13, 64);
            const float s6 = __shfl(acc2, 14, 64), s7 = __shfl(acc2, 15, 64);
            float znp;
            {
#pragma clang fp contract(off)
                const float L = ((r0 + r1) + (r2 + r3)) + ((r4 + r5) + (r6 + r7));
                const float R = ((s0 + s1) + (s2 + s3)) + ((s4 + s5) + (s6 + s7));
                znp = L + R;
            }
            const int lb = lane & ~3;
            const float l0 = __shfl(acc, lb + 0, 64), l1 = __shfl(acc, lb + 1, 64);
            const float l2 = __shfl(acc, lb + 2, 64), l3 = __shfl(acc, lb + 3, 64);
            u64 key = ~0ull;
            {
#pragma clang fp contract(off)
                const float dot = (l0 + l1) + (l2 + l3);
                const float S   = znp + enorm_np[k];
                const float tw  = 2.0f * dot;
                const float d   = S - tw;
                if ((lane & 3) == 0) key = ((u64)ordf(d) << 32) | (u32)k;
            }
#pragma unroll
            for (int m = 1; m < 64; m <<= 1) key = min64(key, __shfl_xor(key, m, 64));
            if (lane == 0) atomicMin(&minslot[ei], key);
        }
    }
}

// ------------- fin3: write idx for list3 entries from minslot
__global__ void fin3_kernel(const int* __restrict__ cnt,
                            const int* __restrict__ list3,
                            const u64* __restrict__ minslot,
                            int* __restrict__ idx_i, float* __restrict__ idx_f) {
    const int nflag = min(cnt[1], LISTCAP);
    for (int i = threadIdx.x; i < nflag; i += 256) {
        const u64 key = minslot[i];
        const int k = (int)(key & 0xffffffffu);
        const int n = list3[i];
        idx_i[n] = k;
        idx_f[n] = (float)k;
    }
}

// ---------------------------------------------------------------- z_q + loss
// 512 blocks: blk = b*16 + cg (16-channel group).
__global__ __launch_bounds__(256)
void zq_loss_kernel(const float* __restrict__ z, const float* __restrict__ emb,
                    const int* __restrict__ idx_i, float* __restrict__ zq,
                    double* __restrict__ lpart) {
    const int blk = blockIdx.x;
    const int b   = blk >> 4;
    const int cg  = blk & 15;
    const int t   = threadIdx.x;
    const int hw  = t * 4;
    const int n0  = b * HW + hw;

    const float* e0 = emb + (size_t)idx_i[n0 + 0] * CDIM + cg * 16;
    const float* e1 = emb + (size_t)idx_i[n0 + 1] * CDIM + cg * 16;
    const float* e2 = emb + (size_t)idx_i[n0 + 2] * CDIM + cg * 16;
    const float* e3 = emb + (size_t)idx_i[n0 + 3] * CDIM + cg * 16;

    const size_t base = ((size_t)b * CDIM + cg * 16) * HW + hw;
    const float* zb = z + base;
    float*       ob = zq + base;

    float ls = 0.f;
#pragma unroll
    for (int c4 = 0; c4 < 4; ++c4) {
        const float4 a0 = *(const float4*)(e0 + 4 * c4);
        const float4 a1 = *(const float4*)(e1 + 4 * c4);
        const float4 a2 = *(const float4*)(e2 + 4 * c4);
        const float4 a3 = *(const float4*)(e3 + 4 * c4);
        const float av0[4] = {a0.x, a0.y, a0.z, a0.w};
        const float av1[4] = {a1.x, a1.y, a1.z, a1.w};
        const float av2[4] = {a2.x, a2.y, a2.z, a2.w};
        const float av3[4] = {a3.x, a3.y, a3.z, a3.w};
#pragma unroll
        for (int cj = 0; cj < 4; ++cj) {
            const size_t off = (size_t)(c4 * 4 + cj) * HW;
            const f32x4 zv = __builtin_nontemporal_load((const f32x4*)(zb + off));
            f32x4 o;
            o[0] = av0[cj]; o[1] = av1[cj]; o[2] = av2[cj]; o[3] = av3[cj];
            __builtin_nontemporal_store(o, (f32x4*)(ob + off));
            const float d0 = o[0] - zv[0], d1 = o[1] - zv[1];
            const float d2 = o[2] - zv[2], d3 = o[3] - zv[3];
            ls += d0 * d0 + d1 * d1 + d2 * d2 + d3 * d3;
        }
    }

    __shared__ float red[256];
    red[t] = ls;
    __syncthreads();
    if (t < 128) red[t] += red[t + 128];
    __syncthreads();
    if (t < 64) {
        float s = red[t] + red[t + 64];
#pragma unroll
        for (int off = 32; off > 0; off >>= 1) s += __shfl_down(s, off, 64);
        if (t == 0) lpart[blk] = (double)s;
    }
}

__global__ void loss_fin_kernel(const double* __restrict__ lpart,
                                float* __restrict__ loss_out) {
    const int t = threadIdx.x;   // 64 threads; 512 partials
    double s = 0.0;
#pragma unroll
    for (int i = 0; i < 8; ++i) s += lpart[t * 8 + i];
#pragma unroll
    for (int off = 32; off > 0; off >>= 1) s += __shfl_down(s, off, 64);
    if (t == 0)
        loss_out[0] = (float)(0.25 * s / (double)((size_t)BB * CDIM * HW));
}

// ---------------------------------------------------------------- launch
extern "C" void kernel_launch(void* const* d_in, const int* in_sizes, int n_in,
                              void* d_out, int out_size, void* d_ws, size_t ws_size,
                              hipStream_t stream) {
    const float* z   = (const float*)d_in[0];
    const float* emb = (const float*)d_in[1];

    float* out  = (float*)d_out;
    float* zq   = out;
    float* loss = out + (size_t)BB * CDIM * HW;
    float* idxf = loss + 1;

    char* ws = (char*)d_ws;
    int*            idx_i   = (int*)(ws);                      // 131072 B
    float*          enorm   = (float*)(ws + 131072);           // 4096 B
    double*         lpart   = (double*)(ws + 135168);          // 4096 B
    int*            cnt     = (int*)(ws + 139264);             // 256 B
    int*            list2   = (int*)(ws + 139520);             // 65536 B
    int*            list3   = (int*)(ws + 205056);             // 65536 B
    unsigned short* ehi     = (unsigned short*)(ws + 270592);  // 524288 B
    u64*            minslot = (u64*)(ws + 794880);             // 131072 B

    prep_kernel<<<64, 256, 0, stream>>>(emb, ehi, enorm, cnt);

    argmin_mfma_kernel<<<NPIX / 64, 256, 0, stream>>>(z, ehi, enorm,
                                                      idx_i, idxf, cnt,
                                                      list2, list3, minslot);
    npfix23_kernel<<<768, 256, 0, stream>>>(z, emb, enorm, cnt, list2, list3,
                                            idx_i, idxf, minslot);
    fin3_kernel<<<1, 256, 0, stream>>>(cnt, list3, minslot, idx_i, idxf);

    zq_loss_kernel<<<BB * 16, 256, 0, stream>>>(z, emb, idx_i, zq, lpart);
    loss_fin_kernel<<<1, 64, 0, stream>>>(lpart, loss);
}